// Round 7
// baseline (336.344 us; speedup 1.0000x reference)
//
#include <hip/hip_runtime.h>
#include <hip/hip_bf16.h>
#include <stdint.h>

#define D_MODEL 1024
#define N_HEADS 16
#define HEAD_DIM 64
#define SEQ_LEN 2048
#define BATCH 2
#define M_TOK (BATCH * SEQ_LEN)   // 4096
#define NQT (SEQ_LEN / 64)        // 32 q-tiles of 64 rows
#define SCL2 0.18033688011112042f // (1/sqrt(64)) * log2(e), folded into q gamma
#define RMS_EPS 1e-8f
#define DEFER_THR 11.5f           // ~8 nats in log2 units (T13)

typedef __bf16 bf16x8 __attribute__((ext_vector_type(8)));
typedef float f32x4 __attribute__((ext_vector_type(4)));
typedef unsigned short us8 __attribute__((ext_vector_type(8)));
typedef unsigned short us4 __attribute__((ext_vector_type(4)));

__device__ __forceinline__ float bf2f(unsigned short u) {
    union { unsigned int i; float f; } x; x.i = ((unsigned int)u) << 16; return x.f;
}
__device__ __forceinline__ unsigned short f2bf(float f) {
    union { float f; unsigned int i; } x; x.f = f;
    unsigned int i = x.i;
    return (unsigned short)((i + 0x7FFFu + ((i >> 16) & 1u)) >> 16);
}
__device__ __forceinline__ f32x4 mfma16(bf16x8 a, bf16x8 b, f32x4 c) {
    return __builtin_amdgcn_mfma_f32_16x16x32_bf16(a, b, c, 0, 0, 0);
}
__device__ __forceinline__ uint32_t cvtpk_bf16(float lo, float hi) {
    uint32_t r;
    asm("v_cvt_pk_bf16_f32 %0, %1, %2" : "=v"(r) : "v"(lo), "v"(hi));
    return r;
}

#define GLOAD16(gp, lp) __builtin_amdgcn_global_load_lds( \
    (__attribute__((address_space(1))) void*)(gp), \
    (__attribute__((address_space(3))) void*)(lp), 16, 0, 0)

__device__ __forceinline__ uint32_t lds_off(void* p) {
    return (uint32_t)(uintptr_t)(__attribute__((address_space(3))) char*)p;
}
__device__ __forceinline__ uint2 ds_tr16(uint32_t addr) {
    uint2 r;
    asm volatile("ds_read_b64_tr_b16 %0, %1" : "=v"(r) : "v"(addr));
    return r;
}

// ---------------- prep: fp32->bf16 converts + RoPE table [i][s] ----------
__global__ void prep_kernel(const float* __restrict__ x,  const float* __restrict__ wq,
                            const float* __restrict__ wk, const float* __restrict__ wv,
                            const float* __restrict__ wo,
                            unsigned short* __restrict__ xb,  unsigned short* __restrict__ wqb,
                            unsigned short* __restrict__ wkb, unsigned short* __restrict__ wvb,
                            unsigned short* __restrict__ wob, float2* __restrict__ tab2) {
    int bid = blockIdx.x;
    if (bid < 8192) {
        int i = bid * 256 + threadIdx.x;
        const float* s; unsigned short* d; int j;
        if (i < 1048576) { s = x; d = xb; j = i; }
        else {
            int t = i - 1048576; int mm = t >> 18; j = t & 262143;
            s = mm == 0 ? wq : mm == 1 ? wk : mm == 2 ? wv : wo;
            d = mm == 0 ? wqb : mm == 1 ? wkb : mm == 2 ? wvb : wob;
        }
        float4 v = reinterpret_cast<const float4*>(s)[j];
        us4 o = { f2bf(v.x), f2bf(v.y), f2bf(v.z), f2bf(v.w) };
        reinterpret_cast<us4*>(d)[j] = o;
    } else {
        int idx = (bid - 8192) * 256 + threadIdx.x;   // 65536 = 32 i x 2048 s
        int i = idx >> 11, sp = idx & 2047;
        float inv = powf(10000.0f, -(float)(2 * i) / 64.0f);
        float ang = (float)sp * inv;
        tab2[idx] = make_float2(cosf(ang), sinf(ang));  // tab2[i*2048 + s]
    }
}

// ---------------- fused QKV GEMM + RoPE + RMSNorm epilogue (R4-proven) ----
// C[m][n] = sum_k A[m][k]*B[n][k]; 128x128 tile, BK=64, m97 2-phase structure.
// blockIdx.x: 0-7 -> q (rope+rms+prescale), 8-15 -> k (rope+rms), 16-23 -> v.
__global__ __launch_bounds__(256, 2)
void gemm_qkv_kernel(const unsigned short* __restrict__ A,
                     const unsigned short* __restrict__ Bq,
                     const unsigned short* __restrict__ Bk,
                     const unsigned short* __restrict__ Bv,
                     unsigned short* __restrict__ Cq,
                     unsigned short* __restrict__ Ck,
                     unsigned short* __restrict__ Cv,
                     const float* __restrict__ qg,
                     const float* __restrict__ kg,
                     const float2* __restrict__ tab2) {
    const int K = D_MODEL, N = D_MODEL;
    __shared__ __align__(16) char lds[32768];
    char* Ab = lds;
    char* Bb = lds + 16384;

    const int nb = blockIdx.x;
    const int mtype = nb >> 3;          // 0 q, 1 k, 2 v
    const int ncol = (nb & 7) * 128;    // col base within the 1024-wide matrix
    const unsigned short* Bm = mtype == 0 ? Bq : mtype == 1 ? Bk : Bv;
    unsigned short* Cm = mtype == 0 ? Cq : mtype == 1 ? Ck : Cv;

    const int tid = threadIdx.x;
    const int w = tid >> 6, lane = tid & 63;
    const int g = lane >> 4, c15 = lane & 15;
    const int wr = w >> 1, wc = w & 1;
    const int m0 = blockIdx.y * 128;
    const int row_s = tid >> 3, k8 = tid & 7;

    f32x4 acc[4][4] = {};
    const int NT = K >> 6;

    for (int kt = 0; kt < NT; ++kt) {
        const int kb = kt * 64;
        __syncthreads();
#pragma unroll
        for (int r = 0; r < 4; ++r) {
            int row = r * 32 + row_s;
            GLOAD16(A + (size_t)(m0 + row) * K + kb + k8 * 8, Ab + r * 4096 + w * 1024);
            GLOAD16(Bm + (size_t)(ncol + row) * K + kb + k8 * 8, Bb + r * 4096 + w * 1024);
        }
        __syncthreads();

        bf16x8 af[4][2], bfr[4][2];
#pragma unroll
        for (int mi = 0; mi < 4; ++mi)
#pragma unroll
            for (int kk = 0; kk < 2; ++kk) {
                af[mi][kk]  = *reinterpret_cast<const bf16x8*>(Ab + (wr * 64 + mi * 16 + c15) * 128 + kk * 64 + g * 16);
                bfr[mi][kk] = *reinterpret_cast<const bf16x8*>(Bb + (wc * 64 + mi * 16 + c15) * 128 + kk * 64 + g * 16);
            }
#pragma unroll
        for (int mi = 0; mi < 4; ++mi)
#pragma unroll
            for (int nj = 0; nj < 4; ++nj)
#pragma unroll
                for (int kk = 0; kk < 2; ++kk)
                    acc[mi][nj] = mfma16(af[mi][kk], bfr[nj][kk], acc[mi][nj]);
    }

    if (mtype == 2) {   // V: plain bf16 write
#pragma unroll
        for (int mi = 0; mi < 4; ++mi)
#pragma unroll
            for (int nj = 0; nj < 4; ++nj)
#pragma unroll
                for (int r = 0; r < 4; ++r) {
                    int row = m0 + wr * 64 + mi * 16 + g * 4 + r;
                    int col = ncol + wc * 64 + nj * 16 + c15;
                    Cm[(size_t)row * N + col] = f2bf(acc[mi][nj][r]);
                }
        return;
    }

    // ---- RoPE + RMSNorm epilogue (wave's 64 cols == one full head) ----
    const float* gam = mtype ? kg : qg;
    const float qsc = mtype ? 1.0f : SCL2;
    float g4[4];
#pragma unroll
    for (int nj = 0; nj < 4; ++nj) g4[nj] = gam[nj * 16 + c15] * qsc;
    const int ihalf = c15 >> 1;    // d>>1 within 16-col group

#pragma unroll
    for (int mi = 0; mi < 4; ++mi) {
        int rbase = m0 + wr * 64 + mi * 16 + g * 4;   // 4 consecutive rows
        int srow = rbase & (SEQ_LEN - 1);             // tiles never cross batch bound
        float2 cs[4][4];                              // [nj][r]
#pragma unroll
        for (int nj = 0; nj < 4; ++nj) {
            const float4* tp = reinterpret_cast<const float4*>(tab2 + (size_t)(nj * 8 + ihalf) * SEQ_LEN + srow);
            float4 lo = tp[0], hi = tp[1];
            cs[nj][0] = make_float2(lo.x, lo.y); cs[nj][1] = make_float2(lo.z, lo.w);
            cs[nj][2] = make_float2(hi.x, hi.y); cs[nj][3] = make_float2(hi.z, hi.w);
        }
        float rot[4][4];
#pragma unroll
        for (int nj = 0; nj < 4; ++nj)
#pragma unroll
            for (int r = 0; r < 4; ++r) {
                float v = acc[mi][nj][r];
                float pv = __shfl_xor(v, 1);
                float c = cs[nj][r].x, s = cs[nj][r].y;
                // even d: e*c - o*s (e=v,o=pv); odd d: e*s + o*c (e=pv,o=v)
                rot[nj][r] = (c15 & 1) ? fmaf(pv, s, v * c) : fmaf(-pv, s, v * c);
            }
#pragma unroll
        for (int r = 0; r < 4; ++r) {
            float ss = rot[0][r] * rot[0][r] + rot[1][r] * rot[1][r]
                     + rot[2][r] * rot[2][r] + rot[3][r] * rot[3][r];
            ss += __shfl_xor(ss, 1);
            ss += __shfl_xor(ss, 2);
            ss += __shfl_xor(ss, 4);
            ss += __shfl_xor(ss, 8);
            float rinv = rsqrtf(ss * (1.0f / 64.0f) + RMS_EPS);
#pragma unroll
            for (int nj = 0; nj < 4; ++nj) {
                int col = ncol + wc * 64 + nj * 16 + c15;
                Cm[(size_t)(rbase + r) * N + col] = f2bf(rot[nj][r] * rinv * g4[nj]);
            }
        }
    }
}

// ---------------- proj GEMM: 64x128 tile (512 blocks, 2/CU) --------------
__global__ __launch_bounds__(256, 2)
void gemm_proj_kernel(const unsigned short* __restrict__ A,
                      const unsigned short* __restrict__ B,
                      float* __restrict__ C) {
    const int K = D_MODEL, N = D_MODEL;
    __shared__ __align__(16) char lds[24576];   // A 8K | B 16K
    char* Ab = lds;
    char* Bb = lds + 8192;

    const int tid = threadIdx.x;
    const int w = tid >> 6, lane = tid & 63;
    const int g = lane >> 4, c15 = lane & 15;
    const int wr = w >> 1, wc = w & 1;          // 2x2 waves over 64x128
    const int m0 = blockIdx.y * 64, n0 = blockIdx.x * 128;
    const int row_s = tid >> 3, k8 = tid & 7;

    f32x4 acc[2][4] = {};
    const int NT = K >> 6;

    for (int kt = 0; kt < NT; ++kt) {
        const int kb = kt * 64;
        __syncthreads();
#pragma unroll
        for (int r = 0; r < 2; ++r) {
            int row = r * 32 + row_s;
            GLOAD16(A + (size_t)(m0 + row) * K + kb + k8 * 8, Ab + r * 4096 + w * 1024);
        }
#pragma unroll
        for (int r = 0; r < 4; ++r) {
            int row = r * 32 + row_s;
            GLOAD16(B + (size_t)(n0 + row) * K + kb + k8 * 8, Bb + r * 4096 + w * 1024);
        }
        __syncthreads();

        bf16x8 af[2][2], bfr[4][2];
#pragma unroll
        for (int mi = 0; mi < 2; ++mi)
#pragma unroll
            for (int kk = 0; kk < 2; ++kk)
                af[mi][kk] = *reinterpret_cast<const bf16x8*>(Ab + (wr * 32 + mi * 16 + c15) * 128 + kk * 64 + g * 16);
#pragma unroll
        for (int nj = 0; nj < 4; ++nj)
#pragma unroll
            for (int kk = 0; kk < 2; ++kk)
                bfr[nj][kk] = *reinterpret_cast<const bf16x8*>(Bb + (wc * 64 + nj * 16 + c15) * 128 + kk * 64 + g * 16);
#pragma unroll
        for (int mi = 0; mi < 2; ++mi)
#pragma unroll
            for (int nj = 0; nj < 4; ++nj)
#pragma unroll
                for (int kk = 0; kk < 2; ++kk)
                    acc[mi][nj] = mfma16(af[mi][kk], bfr[nj][kk], acc[mi][nj]);
    }

#pragma unroll
    for (int mi = 0; mi < 2; ++mi)
#pragma unroll
        for (int nj = 0; nj < 4; ++nj)
#pragma unroll
            for (int r = 0; r < 4; ++r) {
                int row = m0 + wr * 32 + mi * 16 + g * 4 + r;
                int col = n0 + wc * 64 + nj * 16 + c15;
                C[(size_t)row * N + col] = acc[mi][nj][r];
            }
}

// ---------------- causal flash attention (single-buffered K/V, 24K LDS) --
// 4 waves, 64 q/block (16/wave), KVBLK=64. Grid (32 qt, 32 bh) = 1024 blocks,
// LPT order (longest first), all resident from t=0 (LDS allows 6/CU).
// Pipeline per tile: QK -> barA (K free, V visible) -> stageK(it+1) ->
// softmax -> PV -> barB (V free, K(it+1) drained) -> stageV(it+1).
__global__ __launch_bounds__(256, 6)
void attn_kernel(const unsigned short* __restrict__ Q,
                 const unsigned short* __restrict__ Kt,
                 const unsigned short* __restrict__ V,
                 unsigned short* __restrict__ O) {
    __shared__ __align__(16) char lds[24576];  // K 8K | V 8K | P 8K
    const int bh = blockIdx.y, b = bh >> 4, h = bh & 15;
    const int tid = threadIdx.x, w = tid >> 6, lane = tid & 63;
    const int g = lane >> 4, c15 = lane & 15;
    char* Pw = lds + 16384 + w * 2048;
    const size_t base_bh = (size_t)b * SEQ_LEN * D_MODEL + (size_t)h * HEAD_DIM;
    const int krow_s = tid >> 3, kcol_s = (tid & 7) * 16;
    const int psw = (c15 & 7) << 4;

    auto stageK = [&](int kb) {
#pragma unroll
        for (int r = 0; r < 2; ++r) {
            int krow = r * 32 + krow_s;
            int cb = kcol_s ^ ((krow & 7) << 4);
            GLOAD16(Kt + base_bh + (size_t)(kb + krow) * D_MODEL + (cb >> 1),
                    lds + r * 4096 + w * 1024);
        }
    };
    auto stageV = [&](int kb) {
#pragma unroll
        for (int r = 0; r < 2; ++r) {
            int e = r * 2048 + tid * 8;               // V subtiled [k/4][d/16][4][16]
            int vk = ((e >> 8) << 2) + ((e >> 4) & 3);
            int vd = (((e >> 6) & 3) << 4) + (e & 15);
            GLOAD16(V + base_bh + (size_t)(kb + vk) * D_MODEL + vd,
                    lds + 8192 + r * 4096 + w * 1024);
        }
    };

    const int qt = (NQT - 1) - blockIdx.x;   // LPT: longest blocks dispatch first
    const int q0 = qt * 64, nt = qt + 1;
    const int q = q0 + w * 16 + c15;
    bf16x8 qf[2];
#pragma unroll
    for (int kk = 0; kk < 2; ++kk)
        qf[kk] = *reinterpret_cast<const bf16x8*>(Q + base_bh + (size_t)q * D_MODEL + kk * 32 + g * 8);
    f32x4 oacc[4] = {};
    float mrun = -1e30f, lrun = 0.f;

    stageK(0);
    stageV(0);
    __syncthreads();
    for (int it = 0; it < nt; ++it) {
        const int kb = it * 64;

        // S^T = K Q^T (reads K region)
        f32x4 sacc[4] = {};
        __builtin_amdgcn_s_setprio(1);
#pragma unroll
        for (int nj = 0; nj < 4; ++nj) {
            int kl = nj * 16 + c15, sw = (kl & 7) << 4;
#pragma unroll
            for (int kk = 0; kk < 2; ++kk) {
                bf16x8 kf = *reinterpret_cast<const bf16x8*>(lds + kl * 128 + ((kk * 64 + g * 16) ^ sw));
                sacc[nj] = mfma16(kf, qf[kk], sacc[nj]);
            }
        }
        __builtin_amdgcn_s_setprio(0);

        __syncthreads();   // (A) all waves done with K; drains own V(it) staging
        if (it + 1 < nt) stageK(kb + 64);   // hides under softmax+PV

        // in-lane online softmax; scores already scaled (log2 units)
        const bool diag = (it == nt - 1);
        float sv[4][4];
        float tmax = -1e30f;
#pragma unroll
        for (int nj = 0; nj < 4; ++nj)
#pragma unroll
            for (int r = 0; r < 4; ++r) {
                float s = sacc[nj][r];
                if (diag && (kb + nj * 16 + g * 4 + r > q)) s = -1e30f;
                sv[nj][r] = s;
                tmax = fmaxf(tmax, s);
            }
        tmax = fmaxf(tmax, __shfl_xor(tmax, 16));
        tmax = fmaxf(tmax, __shfl_xor(tmax, 32));

        float alpha = 1.0f;
        if (__any(tmax > mrun + DEFER_THR)) {   // T13: defer-max
            float mnew = fmaxf(mrun, tmax);
            alpha = exp2f(mrun - mnew);
            mrun = mnew;
            float ar[4];
#pragma unroll
            for (int r = 0; r < 4; ++r) ar[r] = __shfl(alpha, g * 4 + r, 16);
#pragma unroll
            for (int f = 0; f < 4; ++f)
#pragma unroll
                for (int r = 0; r < 4; ++r) oacc[f][r] *= ar[r];
        }

        float rsum = 0.f;
#pragma unroll
        for (int nj = 0; nj < 4; ++nj) {
            float p0 = exp2f(sv[nj][0] - mrun);
            float p1 = exp2f(sv[nj][1] - mrun);
            float p2 = exp2f(sv[nj][2] - mrun);
            float p3 = exp2f(sv[nj][3] - mrun);
            rsum += (p0 + p1) + (p2 + p3);
            uint2 pw = { cvtpk_bf16(p0, p1), cvtpk_bf16(p2, p3) };
            *reinterpret_cast<uint2*>(Pw + c15 * 128 + ((nj * 32 + g * 8) ^ psw)) = pw;
        }
        rsum += __shfl_xor(rsum, 16);
        rsum += __shfl_xor(rsum, 32);
        lrun = lrun * alpha + rsum;

        // O += P V (reads V region via hardware transpose)
        bf16x8 pf[2];
#pragma unroll
        for (int kk = 0; kk < 2; ++kk)
            pf[kk] = *reinterpret_cast<const bf16x8*>(Pw + c15 * 128 + ((kk * 64 + g * 16) ^ psw));
        uint32_t vbase = lds_off(lds + 8192) + c15 * 8;
        uint2 vt[4][2][2];
#pragma unroll
        for (int f = 0; f < 4; ++f)
#pragma unroll
            for (int kk = 0; kk < 2; ++kk)
#pragma unroll
                for (int hh = 0; hh < 2; ++hh)
                    vt[f][kk][hh] = ds_tr16(vbase + (uint32_t)((kk * 8 + g * 2 + hh) * 512 + f * 128));
        asm volatile("s_waitcnt lgkmcnt(0)" ::: "memory");
        __builtin_amdgcn_sched_barrier(0);
        __builtin_amdgcn_s_setprio(1);
#pragma unroll
        for (int f = 0; f < 4; ++f)
#pragma unroll
            for (int kk = 0; kk < 2; ++kk) {
                union { uint32_t u[4]; bf16x8 v; } fu;
                fu.u[0] = vt[f][kk][0].x; fu.u[1] = vt[f][kk][0].y;
                fu.u[2] = vt[f][kk][1].x; fu.u[3] = vt[f][kk][1].y;
                oacc[f] = mfma16(pf[kk], fu.v, oacc[f]);
            }
        __builtin_amdgcn_s_setprio(0);

        __syncthreads();   // (B) all waves done with V; drains own K(it+1) staging
        if (it + 1 < nt) stageV(kb + 64);   // hides under next tile's QK
    }

    float li = 1.f / lrun;
    float lr[4];
#pragma unroll
    for (int r = 0; r < 4; ++r) lr[r] = __shfl(li, g * 4 + r, 16);
#pragma unroll
    for (int f = 0; f < 4; ++f)
#pragma unroll
        for (int r = 0; r < 4; ++r) {
            int qq = q0 + w * 16 + g * 4 + r;
            O[base_bh + (size_t)qq * D_MODEL + f * 16 + c15] = f2bf(oacc[f][r] * lr[r]);
        }
}

// ---------------- launch ----------------
extern "C" void kernel_launch(void* const* d_in, const int* in_sizes, int n_in,
                              void* d_out, int out_size, void* d_ws, size_t ws_size,
                              hipStream_t stream) {
    const float* x  = (const float*)d_in[0];
    const float* wq = (const float*)d_in[1];
    const float* wk = (const float*)d_in[2];
    const float* wv = (const float*)d_in[3];
    const float* wo = (const float*)d_in[4];
    const float* qg = (const float*)d_in[5];
    const float* kg = (const float*)d_in[6];
    float* out = (float*)d_out;

    char* ws = (char*)d_ws;
    const size_t MB = 1024ull * 1024ull;
    unsigned short* xb  = (unsigned short*)(ws);
    unsigned short* qb  = (unsigned short*)(ws + 8 * MB);
    unsigned short* kb  = (unsigned short*)(ws + 16 * MB);
    unsigned short* vb  = (unsigned short*)(ws + 24 * MB);
    unsigned short* ab  = (unsigned short*)(ws + 32 * MB);
    unsigned short* wqb = (unsigned short*)(ws + 40 * MB);
    unsigned short* wkb = (unsigned short*)(ws + 42 * MB);
    unsigned short* wvb = (unsigned short*)(ws + 44 * MB);
    unsigned short* wob = (unsigned short*)(ws + 46 * MB);
    float2* tab2        = (float2*)(ws + 48 * MB);

    prep_kernel<<<8448, 256, 0, stream>>>(x, wq, wk, wv, wo, xb, wqb, wkb, wvb, wob, tab2);

    gemm_qkv_kernel<<<dim3(24, 32), 256, 0, stream>>>(
        xb, wqb, wkb, wvb, qb, kb, vb, qg, kg, tab2);

    attn_kernel<<<dim3(32, 32), 256, 0, stream>>>(qb, kb, vb, ab);

    gemm_proj_kernel<<<dim3(8, 64), 256, 0, stream>>>(ab, wob, out);
}

// Round 8
// 203.982 us; speedup vs baseline: 1.6489x; 1.6489x over previous
//
#include <hip/hip_runtime.h>
#include <hip/hip_bf16.h>
#include <stdint.h>

#define D_MODEL 1024
#define N_HEADS 16
#define HEAD_DIM 64
#define SEQ_LEN 2048
#define BATCH 2
#define M_TOK (BATCH * SEQ_LEN)   // 4096
#define NQT (SEQ_LEN / 64)        // 32 q-tiles of 64 rows
#define SCL2 0.18033688011112042f // (1/sqrt(64)) * log2(e), folded into q gamma
#define RMS_EPS 1e-8f
#define DEFER_THR 11.5f           // ~8 nats in log2 units (T13)

typedef __bf16 bf16x8 __attribute__((ext_vector_type(8)));
typedef float f32x4 __attribute__((ext_vector_type(4)));
typedef unsigned short us8 __attribute__((ext_vector_type(8)));
typedef unsigned short us4 __attribute__((ext_vector_type(4)));

__device__ __forceinline__ float bf2f(unsigned short u) {
    union { unsigned int i; float f; } x; x.i = ((unsigned int)u) << 16; return x.f;
}
__device__ __forceinline__ unsigned short f2bf(float f) {
    union { float f; unsigned int i; } x; x.f = f;
    unsigned int i = x.i;
    return (unsigned short)((i + 0x7FFFu + ((i >> 16) & 1u)) >> 16);
}
__device__ __forceinline__ f32x4 mfma16(bf16x8 a, bf16x8 b, f32x4 c) {
    return __builtin_amdgcn_mfma_f32_16x16x32_bf16(a, b, c, 0, 0, 0);
}
__device__ __forceinline__ uint32_t cvtpk_bf16(float lo, float hi) {
    uint32_t r;
    asm("v_cvt_pk_bf16_f32 %0, %1, %2" : "=v"(r) : "v"(lo), "v"(hi));
    return r;
}

#define GLOAD16(gp, lp) __builtin_amdgcn_global_load_lds( \
    (__attribute__((address_space(1))) void*)(gp), \
    (__attribute__((address_space(3))) void*)(lp), 16, 0, 0)

__device__ __forceinline__ uint32_t lds_off(void* p) {
    return (uint32_t)(uintptr_t)(__attribute__((address_space(3))) char*)p;
}
__device__ __forceinline__ uint2 ds_tr16(uint32_t addr) {
    uint2 r;
    asm volatile("ds_read_b64_tr_b16 %0, %1" : "=v"(r) : "v"(addr));
    return r;
}

// ---------------- prep: fp32->bf16 converts + RoPE table [i][s] ----------
__global__ void prep_kernel(const float* __restrict__ x,  const float* __restrict__ wq,
                            const float* __restrict__ wk, const float* __restrict__ wv,
                            const float* __restrict__ wo,
                            unsigned short* __restrict__ xb,  unsigned short* __restrict__ wqb,
                            unsigned short* __restrict__ wkb, unsigned short* __restrict__ wvb,
                            unsigned short* __restrict__ wob, float2* __restrict__ tab2) {
    int bid = blockIdx.x;
    if (bid < 8192) {
        int i = bid * 256 + threadIdx.x;
        const float* s; unsigned short* d; int j;
        if (i < 1048576) { s = x; d = xb; j = i; }
        else {
            int t = i - 1048576; int mm = t >> 18; j = t & 262143;
            s = mm == 0 ? wq : mm == 1 ? wk : mm == 2 ? wv : wo;
            d = mm == 0 ? wqb : mm == 1 ? wkb : mm == 2 ? wvb : wob;
        }
        float4 v = reinterpret_cast<const float4*>(s)[j];
        us4 o = { f2bf(v.x), f2bf(v.y), f2bf(v.z), f2bf(v.w) };
        reinterpret_cast<us4*>(d)[j] = o;
    } else {
        int idx = (bid - 8192) * 256 + threadIdx.x;   // 65536 = 32 i x 2048 s
        int i = idx >> 11, sp = idx & 2047;
        float inv = powf(10000.0f, -(float)(2 * i) / 64.0f);
        float ang = (float)sp * inv;
        tab2[idx] = make_float2(cosf(ang), sinf(ang));  // tab2[i*2048 + s]
    }
}

// ---------------- fused QKV GEMM + RoPE + RMSNorm epilogue (R4-proven) ----
// C[m][n] = sum_k A[m][k]*B[n][k]; 128x128 tile, BK=64, m97 2-phase structure.
// blockIdx.x: 0-7 -> q (rope+rms+prescale), 8-15 -> k (rope+rms), 16-23 -> v.
__global__ __launch_bounds__(256, 2)
void gemm_qkv_kernel(const unsigned short* __restrict__ A,
                     const unsigned short* __restrict__ Bq,
                     const unsigned short* __restrict__ Bk,
                     const unsigned short* __restrict__ Bv,
                     unsigned short* __restrict__ Cq,
                     unsigned short* __restrict__ Ck,
                     unsigned short* __restrict__ Cv,
                     const float* __restrict__ qg,
                     const float* __restrict__ kg,
                     const float2* __restrict__ tab2) {
    const int K = D_MODEL, N = D_MODEL;
    __shared__ __align__(16) char lds[32768];
    char* Ab = lds;
    char* Bb = lds + 16384;

    const int nb = blockIdx.x;
    const int mtype = nb >> 3;          // 0 q, 1 k, 2 v
    const int ncol = (nb & 7) * 128;    // col base within the 1024-wide matrix
    const unsigned short* Bm = mtype == 0 ? Bq : mtype == 1 ? Bk : Bv;
    unsigned short* Cm = mtype == 0 ? Cq : mtype == 1 ? Ck : Cv;

    const int tid = threadIdx.x;
    const int w = tid >> 6, lane = tid & 63;
    const int g = lane >> 4, c15 = lane & 15;
    const int wr = w >> 1, wc = w & 1;
    const int m0 = blockIdx.y * 128;
    const int row_s = tid >> 3, k8 = tid & 7;

    f32x4 acc[4][4] = {};
    const int NT = K >> 6;

    for (int kt = 0; kt < NT; ++kt) {
        const int kb = kt * 64;
        __syncthreads();
#pragma unroll
        for (int r = 0; r < 4; ++r) {
            int row = r * 32 + row_s;
            GLOAD16(A + (size_t)(m0 + row) * K + kb + k8 * 8, Ab + r * 4096 + w * 1024);
            GLOAD16(Bm + (size_t)(ncol + row) * K + kb + k8 * 8, Bb + r * 4096 + w * 1024);
        }
        __syncthreads();

        bf16x8 af[4][2], bfr[4][2];
#pragma unroll
        for (int mi = 0; mi < 4; ++mi)
#pragma unroll
            for (int kk = 0; kk < 2; ++kk) {
                af[mi][kk]  = *reinterpret_cast<const bf16x8*>(Ab + (wr * 64 + mi * 16 + c15) * 128 + kk * 64 + g * 16);
                bfr[mi][kk] = *reinterpret_cast<const bf16x8*>(Bb + (wc * 64 + mi * 16 + c15) * 128 + kk * 64 + g * 16);
            }
#pragma unroll
        for (int mi = 0; mi < 4; ++mi)
#pragma unroll
            for (int nj = 0; nj < 4; ++nj)
#pragma unroll
                for (int kk = 0; kk < 2; ++kk)
                    acc[mi][nj] = mfma16(af[mi][kk], bfr[nj][kk], acc[mi][nj]);
    }

    if (mtype == 2) {   // V: plain bf16 write
#pragma unroll
        for (int mi = 0; mi < 4; ++mi)
#pragma unroll
            for (int nj = 0; nj < 4; ++nj)
#pragma unroll
                for (int r = 0; r < 4; ++r) {
                    int row = m0 + wr * 64 + mi * 16 + g * 4 + r;
                    int col = ncol + wc * 64 + nj * 16 + c15;
                    Cm[(size_t)row * N + col] = f2bf(acc[mi][nj][r]);
                }
        return;
    }

    // ---- RoPE + RMSNorm epilogue (wave's 64 cols == one full head) ----
    const float* gam = mtype ? kg : qg;
    const float qsc = mtype ? 1.0f : SCL2;
    float g4[4];
#pragma unroll
    for (int nj = 0; nj < 4; ++nj) g4[nj] = gam[nj * 16 + c15] * qsc;
    const int ihalf = c15 >> 1;    // d>>1 within 16-col group

#pragma unroll
    for (int mi = 0; mi < 4; ++mi) {
        int rbase = m0 + wr * 64 + mi * 16 + g * 4;   // 4 consecutive rows
        int srow = rbase & (SEQ_LEN - 1);             // tiles never cross batch bound
        float2 cs[4][4];                              // [nj][r]
#pragma unroll
        for (int nj = 0; nj < 4; ++nj) {
            const float4* tp = reinterpret_cast<const float4*>(tab2 + (size_t)(nj * 8 + ihalf) * SEQ_LEN + srow);
            float4 lo = tp[0], hi = tp[1];
            cs[nj][0] = make_float2(lo.x, lo.y); cs[nj][1] = make_float2(lo.z, lo.w);
            cs[nj][2] = make_float2(hi.x, hi.y); cs[nj][3] = make_float2(hi.z, hi.w);
        }
        float rot[4][4];
#pragma unroll
        for (int nj = 0; nj < 4; ++nj)
#pragma unroll
            for (int r = 0; r < 4; ++r) {
                float v = acc[mi][nj][r];
                float pv = __shfl_xor(v, 1);
                float c = cs[nj][r].x, s = cs[nj][r].y;
                // even d: e*c - o*s (e=v,o=pv); odd d: e*s + o*c (e=pv,o=v)
                rot[nj][r] = (c15 & 1) ? fmaf(pv, s, v * c) : fmaf(-pv, s, v * c);
            }
#pragma unroll
        for (int r = 0; r < 4; ++r) {
            float ss = rot[0][r] * rot[0][r] + rot[1][r] * rot[1][r]
                     + rot[2][r] * rot[2][r] + rot[3][r] * rot[3][r];
            ss += __shfl_xor(ss, 1);
            ss += __shfl_xor(ss, 2);
            ss += __shfl_xor(ss, 4);
            ss += __shfl_xor(ss, 8);
            float rinv = rsqrtf(ss * (1.0f / 64.0f) + RMS_EPS);
#pragma unroll
            for (int nj = 0; nj < 4; ++nj) {
                int col = ncol + wc * 64 + nj * 16 + c15;
                Cm[(size_t)(rbase + r) * N + col] = f2bf(rot[nj][r] * rinv * g4[nj]);
            }
        }
    }
}

// ---------------- proj GEMM: 64x128 tile (512 blocks, 2/CU) --------------
__global__ __launch_bounds__(256, 2)
void gemm_proj_kernel(const unsigned short* __restrict__ A,
                      const unsigned short* __restrict__ B,
                      float* __restrict__ C) {
    const int K = D_MODEL, N = D_MODEL;
    __shared__ __align__(16) char lds[24576];   // A 8K | B 16K
    char* Ab = lds;
    char* Bb = lds + 8192;

    const int tid = threadIdx.x;
    const int w = tid >> 6, lane = tid & 63;
    const int g = lane >> 4, c15 = lane & 15;
    const int wr = w >> 1, wc = w & 1;          // 2x2 waves over 64x128
    const int m0 = blockIdx.y * 64, n0 = blockIdx.x * 128;
    const int row_s = tid >> 3, k8 = tid & 7;

    f32x4 acc[2][4] = {};
    const int NT = K >> 6;

    for (int kt = 0; kt < NT; ++kt) {
        const int kb = kt * 64;
        __syncthreads();
#pragma unroll
        for (int r = 0; r < 2; ++r) {
            int row = r * 32 + row_s;
            GLOAD16(A + (size_t)(m0 + row) * K + kb + k8 * 8, Ab + r * 4096 + w * 1024);
        }
#pragma unroll
        for (int r = 0; r < 4; ++r) {
            int row = r * 32 + row_s;
            GLOAD16(B + (size_t)(n0 + row) * K + kb + k8 * 8, Bb + r * 4096 + w * 1024);
        }
        __syncthreads();

        bf16x8 af[2][2], bfr[4][2];
#pragma unroll
        for (int mi = 0; mi < 2; ++mi)
#pragma unroll
            for (int kk = 0; kk < 2; ++kk)
                af[mi][kk] = *reinterpret_cast<const bf16x8*>(Ab + (wr * 32 + mi * 16 + c15) * 128 + kk * 64 + g * 16);
#pragma unroll
        for (int nj = 0; nj < 4; ++nj)
#pragma unroll
            for (int kk = 0; kk < 2; ++kk)
                bfr[nj][kk] = *reinterpret_cast<const bf16x8*>(Bb + (wc * 64 + nj * 16 + c15) * 128 + kk * 64 + g * 16);
#pragma unroll
        for (int mi = 0; mi < 2; ++mi)
#pragma unroll
            for (int nj = 0; nj < 4; ++nj)
#pragma unroll
                for (int kk = 0; kk < 2; ++kk)
                    acc[mi][nj] = mfma16(af[mi][kk], bfr[nj][kk], acc[mi][nj]);
    }

#pragma unroll
    for (int mi = 0; mi < 2; ++mi)
#pragma unroll
        for (int nj = 0; nj < 4; ++nj)
#pragma unroll
            for (int r = 0; r < 4; ++r) {
                int row = m0 + wr * 32 + mi * 16 + g * 4 + r;
                int col = n0 + wc * 64 + nj * 16 + c15;
                C[(size_t)row * N + col] = acc[mi][nj][r];
            }
}

// ---------------- causal flash attention (K dbuf + V single, 32K LDS) ----
// 4 waves, 64 q/block (16/wave), KVBLK=64. Grid (32,32) = 1024 blocks.
// qt = 31 - ((x + y) & 31): LPT (longest first) + per-CU stagger so
// co-scheduled blocks get different qt (balanced per-CU work).
// Body: stageV(it)+stageK(it+1) -> QK -> softmax -> MID bar (drain) -> PV -> END bar.
__global__ __launch_bounds__(256, 4)
void attn_kernel(const unsigned short* __restrict__ Q,
                 const unsigned short* __restrict__ Kt,
                 const unsigned short* __restrict__ V,
                 unsigned short* __restrict__ O) {
    __shared__ __align__(16) char lds[32768];  // K dbuf 16K | V 8K | P 8K
    const int bh = blockIdx.y, b = bh >> 4, h = bh & 15;
    const int tid = threadIdx.x, w = tid >> 6, lane = tid & 63;
    const int g = lane >> 4, c15 = lane & 15;
    char* Pw = lds + 24576 + w * 2048;
    const size_t base_bh = (size_t)b * SEQ_LEN * D_MODEL + (size_t)h * HEAD_DIM;
    const int krow_s = tid >> 3, kcol_s = (tid & 7) * 16;
    const int psw = (c15 & 7) << 4;

    auto stageK = [&](int buf, int kb) {
#pragma unroll
        for (int r = 0; r < 2; ++r) {
            int krow = r * 32 + krow_s;
            int cb = kcol_s ^ ((krow & 7) << 4);
            GLOAD16(Kt + base_bh + (size_t)(kb + krow) * D_MODEL + (cb >> 1),
                    lds + buf * 8192 + r * 4096 + w * 1024);
        }
    };
    auto stageV = [&](int kb) {
#pragma unroll
        for (int r = 0; r < 2; ++r) {
            int e = r * 2048 + tid * 8;               // V subtiled [k/4][d/16][4][16]
            int vk = ((e >> 8) << 2) + ((e >> 4) & 3);
            int vd = (((e >> 6) & 3) << 4) + (e & 15);
            GLOAD16(V + base_bh + (size_t)(kb + vk) * D_MODEL + vd,
                    lds + 16384 + r * 4096 + w * 1024);
        }
    };

    const int qt = (NQT - 1) - ((blockIdx.x + blockIdx.y) & (NQT - 1));
    const int q0 = qt * 64, nt = qt + 1;
    const int q = q0 + w * 16 + c15;
    bf16x8 qf[2];
#pragma unroll
    for (int kk = 0; kk < 2; ++kk)
        qf[kk] = *reinterpret_cast<const bf16x8*>(Q + base_bh + (size_t)q * D_MODEL + kk * 32 + g * 8);
    f32x4 oacc[4] = {};
    float mrun = -1e30f, lrun = 0.f;

    stageK(0, 0);
    __syncthreads();   // K(0) visible
    for (int it = 0; it < nt; ++it) {
        const int cur = it & 1, kb = it * 64;

        stageV(kb);                              // V for THIS tile (drained at MID)
        if (it + 1 < nt) stageK(cur ^ 1, kb + 64);   // K for NEXT tile

        // S^T = K Q^T (reads K(cur); staged last tile, drained at prior MID)
        f32x4 sacc[4] = {};
        char* Kc = lds + cur * 8192;
        __builtin_amdgcn_s_setprio(1);
#pragma unroll
        for (int nj = 0; nj < 4; ++nj) {
            int kl = nj * 16 + c15, sw = (kl & 7) << 4;
#pragma unroll
            for (int kk = 0; kk < 2; ++kk) {
                bf16x8 kf = *reinterpret_cast<const bf16x8*>(Kc + kl * 128 + ((kk * 64 + g * 16) ^ sw));
                sacc[nj] = mfma16(kf, qf[kk], sacc[nj]);
            }
        }
        __builtin_amdgcn_s_setprio(0);

        // in-lane online softmax; scores already scaled (log2 units)
        const bool diag = (it == nt - 1);
        float sv[4][4];
        float tmax = -1e30f;
#pragma unroll
        for (int nj = 0; nj < 4; ++nj)
#pragma unroll
            for (int r = 0; r < 4; ++r) {
                float s = sacc[nj][r];
                if (diag && (kb + nj * 16 + g * 4 + r > q)) s = -1e30f;
                sv[nj][r] = s;
                tmax = fmaxf(tmax, s);
            }
        tmax = fmaxf(tmax, __shfl_xor(tmax, 16));
        tmax = fmaxf(tmax, __shfl_xor(tmax, 32));

        float alpha = 1.0f;
        if (__any(tmax > mrun + DEFER_THR)) {   // T13: defer-max
            float mnew = fmaxf(mrun, tmax);
            alpha = exp2f(mrun - mnew);
            mrun = mnew;
            float ar[4];
#pragma unroll
            for (int r = 0; r < 4; ++r) ar[r] = __shfl(alpha, g * 4 + r, 16);
#pragma unroll
            for (int f = 0; f < 4; ++f)
#pragma unroll
                for (int r = 0; r < 4; ++r) oacc[f][r] *= ar[r];
        }

        float rsum = 0.f;
#pragma unroll
        for (int nj = 0; nj < 4; ++nj) {
            float p0 = exp2f(sv[nj][0] - mrun);
            float p1 = exp2f(sv[nj][1] - mrun);
            float p2 = exp2f(sv[nj][2] - mrun);
            float p3 = exp2f(sv[nj][3] - mrun);
            rsum += (p0 + p1) + (p2 + p3);
            uint2 pw = { cvtpk_bf16(p0, p1), cvtpk_bf16(p2, p3) };
            *reinterpret_cast<uint2*>(Pw + c15 * 128 + ((nj * 32 + g * 8) ^ psw)) = pw;
        }
        rsum += __shfl_xor(rsum, 16);
        rsum += __shfl_xor(rsum, 32);
        lrun = lrun * alpha + rsum;

        __syncthreads();   // MID: drains stageV(it)+stageK(it+1); all waves past QK

        // O += P V (reads V region via hardware transpose)
        bf16x8 pf[2];
#pragma unroll
        for (int kk = 0; kk < 2; ++kk)
            pf[kk] = *reinterpret_cast<const bf16x8*>(Pw + c15 * 128 + ((kk * 64 + g * 16) ^ psw));
        uint32_t vbase = lds_off(lds + 16384) + c15 * 8;
        uint2 vt[4][2][2];
#pragma unroll
        for (int f = 0; f < 4; ++f)
#pragma unroll
            for (int kk = 0; kk < 2; ++kk)
#pragma unroll
                for (int hh = 0; hh < 2; ++hh)
                    vt[f][kk][hh] = ds_tr16(vbase + (uint32_t)((kk * 8 + g * 2 + hh) * 512 + f * 128));
        asm volatile("s_waitcnt lgkmcnt(0)" ::: "memory");
        __builtin_amdgcn_sched_barrier(0);
        __builtin_amdgcn_s_setprio(1);
#pragma unroll
        for (int f = 0; f < 4; ++f)
#pragma unroll
            for (int kk = 0; kk < 2; ++kk) {
                union { uint32_t u[4]; bf16x8 v; } fu;
                fu.u[0] = vt[f][kk][0].x; fu.u[1] = vt[f][kk][0].y;
                fu.u[2] = vt[f][kk][1].x; fu.u[3] = vt[f][kk][1].y;
                oacc[f] = mfma16(pf[kk], fu.v, oacc[f]);
            }
        __builtin_amdgcn_s_setprio(0);

        __syncthreads();   // END: all waves done with V(it) -> next stageV safe
    }

    float li = 1.f / lrun;
    float lr[4];
#pragma unroll
    for (int r = 0; r < 4; ++r) lr[r] = __shfl(li, g * 4 + r, 16);
#pragma unroll
    for (int f = 0; f < 4; ++f)
#pragma unroll
        for (int r = 0; r < 4; ++r) {
            int qq = q0 + w * 16 + g * 4 + r;
            O[base_bh + (size_t)qq * D_MODEL + f * 16 + c15] = f2bf(oacc[f][r] * lr[r]);
        }
}

// ---------------- launch ----------------
extern "C" void kernel_launch(void* const* d_in, const int* in_sizes, int n_in,
                              void* d_out, int out_size, void* d_ws, size_t ws_size,
                              hipStream_t stream) {
    const float* x  = (const float*)d_in[0];
    const float* wq = (const float*)d_in[1];
    const float* wk = (const float*)d_in[2];
    const float* wv = (const float*)d_in[3];
    const float* wo = (const float*)d_in[4];
    const float* qg = (const float*)d_in[5];
    const float* kg = (const float*)d_in[6];
    float* out = (float*)d_out;

    char* ws = (char*)d_ws;
    const size_t MB = 1024ull * 1024ull;
    unsigned short* xb  = (unsigned short*)(ws);
    unsigned short* qb  = (unsigned short*)(ws + 8 * MB);
    unsigned short* kb  = (unsigned short*)(ws + 16 * MB);
    unsigned short* vb  = (unsigned short*)(ws + 24 * MB);
    unsigned short* ab  = (unsigned short*)(ws + 32 * MB);
    unsigned short* wqb = (unsigned short*)(ws + 40 * MB);
    unsigned short* wkb = (unsigned short*)(ws + 42 * MB);
    unsigned short* wvb = (unsigned short*)(ws + 44 * MB);
    unsigned short* wob = (unsigned short*)(ws + 46 * MB);
    float2* tab2        = (float2*)(ws + 48 * MB);

    prep_kernel<<<8448, 256, 0, stream>>>(x, wq, wk, wv, wo, xb, wqb, wkb, wvb, wob, tab2);

    gemm_qkv_kernel<<<dim3(24, 32), 256, 0, stream>>>(
        xb, wqb, wkb, wvb, qb, kb, vb, qg, kg, tab2);

    attn_kernel<<<dim3(32, 32), 256, 0, stream>>>(qb, kb, vb, ab);

    gemm_proj_kernel<<<dim3(8, 64), 256, 0, stream>>>(ab, wob, out);
}

// Round 9
// 202.145 us; speedup vs baseline: 1.6639x; 1.0091x over previous
//
#include <hip/hip_runtime.h>
#include <hip/hip_bf16.h>
#include <stdint.h>

#define D_MODEL 1024
#define N_HEADS 16
#define HEAD_DIM 64
#define SEQ_LEN 2048
#define BATCH 2
#define M_TOK (BATCH * SEQ_LEN)   // 4096
#define NQT (SEQ_LEN / 64)        // 32 q-tiles of 64 rows
#define SCL2 0.18033688011112042f // (1/sqrt(64)) * log2(e), folded into q gamma
#define RMS_EPS 1e-8f
#define DEFER_THR 11.5f           // ~8 nats in log2 units (T13)

typedef __bf16 bf16x8 __attribute__((ext_vector_type(8)));
typedef float f32x4 __attribute__((ext_vector_type(4)));
typedef unsigned short us8 __attribute__((ext_vector_type(8)));
typedef unsigned short us4 __attribute__((ext_vector_type(4)));

__device__ __forceinline__ float bf2f(unsigned short u) {
    union { unsigned int i; float f; } x; x.i = ((unsigned int)u) << 16; return x.f;
}
__device__ __forceinline__ unsigned short f2bf(float f) {
    union { float f; unsigned int i; } x; x.f = f;
    unsigned int i = x.i;
    return (unsigned short)((i + 0x7FFFu + ((i >> 16) & 1u)) >> 16);
}
__device__ __forceinline__ f32x4 mfma16(bf16x8 a, bf16x8 b, f32x4 c) {
    return __builtin_amdgcn_mfma_f32_16x16x32_bf16(a, b, c, 0, 0, 0);
}
__device__ __forceinline__ uint32_t cvtpk_bf16(float lo, float hi) {
    uint32_t r;
    asm("v_cvt_pk_bf16_f32 %0, %1, %2" : "=v"(r) : "v"(lo), "v"(hi));
    return r;
}

#define GLOAD16(gp, lp) __builtin_amdgcn_global_load_lds( \
    (__attribute__((address_space(1))) void*)(gp), \
    (__attribute__((address_space(3))) void*)(lp), 16, 0, 0)

__device__ __forceinline__ uint32_t lds_off(void* p) {
    return (uint32_t)(uintptr_t)(__attribute__((address_space(3))) char*)p;
}
__device__ __forceinline__ uint2 ds_tr16(uint32_t addr) {
    uint2 r;
    asm volatile("ds_read_b64_tr_b16 %0, %1" : "=v"(r) : "v"(addr));
    return r;
}

// ---------------- prep: fp32->bf16 converts + RoPE table [i][s] ----------
__global__ void prep_kernel(const float* __restrict__ x,  const float* __restrict__ wq,
                            const float* __restrict__ wk, const float* __restrict__ wv,
                            const float* __restrict__ wo,
                            unsigned short* __restrict__ xb,  unsigned short* __restrict__ wqb,
                            unsigned short* __restrict__ wkb, unsigned short* __restrict__ wvb,
                            unsigned short* __restrict__ wob, float2* __restrict__ tab2) {
    int bid = blockIdx.x;
    if (bid < 8192) {
        int i = bid * 256 + threadIdx.x;
        const float* s; unsigned short* d; int j;
        if (i < 1048576) { s = x; d = xb; j = i; }
        else {
            int t = i - 1048576; int mm = t >> 18; j = t & 262143;
            s = mm == 0 ? wq : mm == 1 ? wk : mm == 2 ? wv : wo;
            d = mm == 0 ? wqb : mm == 1 ? wkb : mm == 2 ? wvb : wob;
        }
        float4 v = reinterpret_cast<const float4*>(s)[j];
        us4 o = { f2bf(v.x), f2bf(v.y), f2bf(v.z), f2bf(v.w) };
        reinterpret_cast<us4*>(d)[j] = o;
    } else {
        int idx = (bid - 8192) * 256 + threadIdx.x;   // 65536 = 32 i x 2048 s
        int i = idx >> 11, sp = idx & 2047;
        float inv = powf(10000.0f, -(float)(2 * i) / 64.0f);
        float ang = (float)sp * inv;
        tab2[idx] = make_float2(cosf(ang), sinf(ang));  // tab2[i*2048 + s]
    }
}

// ---------------- fused QKV GEMM + RoPE + RMSNorm epilogue (R4-proven) ----
// C[m][n] = sum_k A[m][k]*B[n][k]; 128x128 tile, BK=64, m97 2-phase structure.
// blockIdx.x: 0-7 -> q (rope+rms+prescale), 8-15 -> k (rope+rms), 16-23 -> v.
__global__ __launch_bounds__(256, 2)
void gemm_qkv_kernel(const unsigned short* __restrict__ A,
                     const unsigned short* __restrict__ Bq,
                     const unsigned short* __restrict__ Bk,
                     const unsigned short* __restrict__ Bv,
                     unsigned short* __restrict__ Cq,
                     unsigned short* __restrict__ Ck,
                     unsigned short* __restrict__ Cv,
                     const float* __restrict__ qg,
                     const float* __restrict__ kg,
                     const float2* __restrict__ tab2) {
    const int K = D_MODEL, N = D_MODEL;
    __shared__ __align__(16) char lds[32768];
    char* Ab = lds;
    char* Bb = lds + 16384;

    const int nb = blockIdx.x;
    const int mtype = nb >> 3;          // 0 q, 1 k, 2 v
    const int ncol = (nb & 7) * 128;    // col base within the 1024-wide matrix
    const unsigned short* Bm = mtype == 0 ? Bq : mtype == 1 ? Bk : Bv;
    unsigned short* Cm = mtype == 0 ? Cq : mtype == 1 ? Ck : Cv;

    const int tid = threadIdx.x;
    const int w = tid >> 6, lane = tid & 63;
    const int g = lane >> 4, c15 = lane & 15;
    const int wr = w >> 1, wc = w & 1;
    const int m0 = blockIdx.y * 128;
    const int row_s = tid >> 3, k8 = tid & 7;

    f32x4 acc[4][4] = {};
    const int NT = K >> 6;

    for (int kt = 0; kt < NT; ++kt) {
        const int kb = kt * 64;
        __syncthreads();
#pragma unroll
        for (int r = 0; r < 4; ++r) {
            int row = r * 32 + row_s;
            GLOAD16(A + (size_t)(m0 + row) * K + kb + k8 * 8, Ab + r * 4096 + w * 1024);
            GLOAD16(Bm + (size_t)(ncol + row) * K + kb + k8 * 8, Bb + r * 4096 + w * 1024);
        }
        __syncthreads();

        bf16x8 af[4][2], bfr[4][2];
#pragma unroll
        for (int mi = 0; mi < 4; ++mi)
#pragma unroll
            for (int kk = 0; kk < 2; ++kk) {
                af[mi][kk]  = *reinterpret_cast<const bf16x8*>(Ab + (wr * 64 + mi * 16 + c15) * 128 + kk * 64 + g * 16);
                bfr[mi][kk] = *reinterpret_cast<const bf16x8*>(Bb + (wc * 64 + mi * 16 + c15) * 128 + kk * 64 + g * 16);
            }
#pragma unroll
        for (int mi = 0; mi < 4; ++mi)
#pragma unroll
            for (int nj = 0; nj < 4; ++nj)
#pragma unroll
                for (int kk = 0; kk < 2; ++kk)
                    acc[mi][nj] = mfma16(af[mi][kk], bfr[nj][kk], acc[mi][nj]);
    }

    if (mtype == 2) {   // V: plain bf16 write
#pragma unroll
        for (int mi = 0; mi < 4; ++mi)
#pragma unroll
            for (int nj = 0; nj < 4; ++nj)
#pragma unroll
                for (int r = 0; r < 4; ++r) {
                    int row = m0 + wr * 64 + mi * 16 + g * 4 + r;
                    int col = ncol + wc * 64 + nj * 16 + c15;
                    Cm[(size_t)row * N + col] = f2bf(acc[mi][nj][r]);
                }
        return;
    }

    // ---- RoPE + RMSNorm epilogue (wave's 64 cols == one full head) ----
    const float* gam = mtype ? kg : qg;
    const float qsc = mtype ? 1.0f : SCL2;
    float g4[4];
#pragma unroll
    for (int nj = 0; nj < 4; ++nj) g4[nj] = gam[nj * 16 + c15] * qsc;
    const int ihalf = c15 >> 1;    // d>>1 within 16-col group

#pragma unroll
    for (int mi = 0; mi < 4; ++mi) {
        int rbase = m0 + wr * 64 + mi * 16 + g * 4;   // 4 consecutive rows
        int srow = rbase & (SEQ_LEN - 1);             // tiles never cross batch bound
        float2 cs[4][4];                              // [nj][r]
#pragma unroll
        for (int nj = 0; nj < 4; ++nj) {
            const float4* tp = reinterpret_cast<const float4*>(tab2 + (size_t)(nj * 8 + ihalf) * SEQ_LEN + srow);
            float4 lo = tp[0], hi = tp[1];
            cs[nj][0] = make_float2(lo.x, lo.y); cs[nj][1] = make_float2(lo.z, lo.w);
            cs[nj][2] = make_float2(hi.x, hi.y); cs[nj][3] = make_float2(hi.z, hi.w);
        }
        float rot[4][4];
#pragma unroll
        for (int nj = 0; nj < 4; ++nj)
#pragma unroll
            for (int r = 0; r < 4; ++r) {
                float v = acc[mi][nj][r];
                float pv = __shfl_xor(v, 1);
                float c = cs[nj][r].x, s = cs[nj][r].y;
                // even d: e*c - o*s (e=v,o=pv); odd d: e*s + o*c (e=pv,o=v)
                rot[nj][r] = (c15 & 1) ? fmaf(pv, s, v * c) : fmaf(-pv, s, v * c);
            }
#pragma unroll
        for (int r = 0; r < 4; ++r) {
            float ss = rot[0][r] * rot[0][r] + rot[1][r] * rot[1][r]
                     + rot[2][r] * rot[2][r] + rot[3][r] * rot[3][r];
            ss += __shfl_xor(ss, 1);
            ss += __shfl_xor(ss, 2);
            ss += __shfl_xor(ss, 4);
            ss += __shfl_xor(ss, 8);
            float rinv = rsqrtf(ss * (1.0f / 64.0f) + RMS_EPS);
#pragma unroll
            for (int nj = 0; nj < 4; ++nj) {
                int col = ncol + wc * 64 + nj * 16 + c15;
                Cm[(size_t)(rbase + r) * N + col] = f2bf(rot[nj][r] * rinv * g4[nj]);
            }
        }
    }
}

// ---------------- proj GEMM: 128x128 tile, qkv-identical loop, fp32 out --
// grid (8, 32) = 256 blocks; same MFMA:ds_read ratio as the proven qkv loop.
__global__ __launch_bounds__(256, 2)
void gemm_proj_kernel(const unsigned short* __restrict__ A,
                      const unsigned short* __restrict__ B,
                      float* __restrict__ C) {
    const int K = D_MODEL, N = D_MODEL;
    __shared__ __align__(16) char lds[32768];   // A 16K | B 16K
    char* Ab = lds;
    char* Bb = lds + 16384;

    const int tid = threadIdx.x;
    const int w = tid >> 6, lane = tid & 63;
    const int g = lane >> 4, c15 = lane & 15;
    const int wr = w >> 1, wc = w & 1;
    const int m0 = blockIdx.y * 128, n0 = blockIdx.x * 128;
    const int row_s = tid >> 3, k8 = tid & 7;

    f32x4 acc[4][4] = {};
    const int NT = K >> 6;

    for (int kt = 0; kt < NT; ++kt) {
        const int kb = kt * 64;
        __syncthreads();
#pragma unroll
        for (int r = 0; r < 4; ++r) {
            int row = r * 32 + row_s;
            GLOAD16(A + (size_t)(m0 + row) * K + kb + k8 * 8, Ab + r * 4096 + w * 1024);
            GLOAD16(B + (size_t)(n0 + row) * K + kb + k8 * 8, Bb + r * 4096 + w * 1024);
        }
        __syncthreads();

        bf16x8 af[4][2], bfr[4][2];
#pragma unroll
        for (int mi = 0; mi < 4; ++mi)
#pragma unroll
            for (int kk = 0; kk < 2; ++kk) {
                af[mi][kk]  = *reinterpret_cast<const bf16x8*>(Ab + (wr * 64 + mi * 16 + c15) * 128 + kk * 64 + g * 16);
                bfr[mi][kk] = *reinterpret_cast<const bf16x8*>(Bb + (wc * 64 + mi * 16 + c15) * 128 + kk * 64 + g * 16);
            }
#pragma unroll
        for (int mi = 0; mi < 4; ++mi)
#pragma unroll
            for (int nj = 0; nj < 4; ++nj)
#pragma unroll
                for (int kk = 0; kk < 2; ++kk)
                    acc[mi][nj] = mfma16(af[mi][kk], bfr[nj][kk], acc[mi][nj]);
    }

#pragma unroll
    for (int mi = 0; mi < 4; ++mi)
#pragma unroll
        for (int nj = 0; nj < 4; ++nj)
#pragma unroll
            for (int r = 0; r < 4; ++r) {
                int row = m0 + wr * 64 + mi * 16 + g * 4 + r;
                int col = n0 + wc * 64 + nj * 16 + c15;
                C[(size_t)row * N + col] = acc[mi][nj][r];
            }
}

// ---------------- causal flash attention (R4-proven: paired, dbuf, 40K) --
// 4 waves, 64 q/block (16/wave), KVBLK=64, dbuf gload_lds staging.
// grid: (16 pairs, 32 bh); pair t & 31-t -> 33 KV tiles/block (balanced).
// Q pre-scaled by SCL2 in the QKV epilogue -> scores already in log2 units.
__global__ __launch_bounds__(256, 2)
void attn_kernel(const unsigned short* __restrict__ Q,
                 const unsigned short* __restrict__ Kt,
                 const unsigned short* __restrict__ V,
                 unsigned short* __restrict__ O) {
    __shared__ __align__(16) char lds[40960];  // K dbuf 16K | V dbuf 16K | P 8K
    const int bh = blockIdx.y, b = bh >> 4, h = bh & 15;
    const int tid = threadIdx.x, w = tid >> 6, lane = tid & 63;
    const int g = lane >> 4, c15 = lane & 15;
    char* Pw = lds + 32768 + w * 2048;
    const size_t base_bh = (size_t)b * SEQ_LEN * D_MODEL + (size_t)h * HEAD_DIM;
    const int krow_s = tid >> 3, kcol_s = (tid & 7) * 16;
    const int psw = (c15 & 7) << 4;

    auto stageKV = [&](int buf, int kb) {
#pragma unroll
        for (int r = 0; r < 2; ++r) {
            int krow = r * 32 + krow_s;
            int cb = kcol_s ^ ((krow & 7) << 4);
            GLOAD16(Kt + base_bh + (size_t)(kb + krow) * D_MODEL + (cb >> 1),
                    lds + buf * 8192 + r * 4096 + w * 1024);
            int e = r * 2048 + tid * 8;
            int vk = ((e >> 8) << 2) + ((e >> 4) & 3);
            int vd = (((e >> 6) & 3) << 4) + (e & 15);
            GLOAD16(V + base_bh + (size_t)(kb + vk) * D_MODEL + vd,
                    lds + 16384 + buf * 8192 + r * 4096 + w * 1024);
        }
    };

#pragma unroll 1
    for (int half = 0; half < 2; ++half) {
        const int qt = half ? (NQT - 1 - blockIdx.x) : blockIdx.x;
        const int q0 = qt * 64, nt = qt + 1;
        const int q = q0 + w * 16 + c15;
        bf16x8 qf[2];
#pragma unroll
        for (int kk = 0; kk < 2; ++kk)
            qf[kk] = *reinterpret_cast<const bf16x8*>(Q + base_bh + (size_t)q * D_MODEL + kk * 32 + g * 8);
        f32x4 oacc[4] = {};
        float mrun = -1e30f, lrun = 0.f;

        stageKV(0, 0);
        __syncthreads();
        for (int it = 0; it < nt; ++it) {
            const int cur = it & 1, kb = it * 64;
            if (it + 1 < nt) stageKV(cur ^ 1, kb + 64);
            char* Kc = lds + cur * 8192;
            char* Vc = lds + 16384 + cur * 8192;

            // S^T = K Q^T
            f32x4 sacc[4] = {};
            __builtin_amdgcn_s_setprio(1);
#pragma unroll
            for (int nj = 0; nj < 4; ++nj) {
                int kl = nj * 16 + c15, sw = (kl & 7) << 4;
#pragma unroll
                for (int kk = 0; kk < 2; ++kk) {
                    bf16x8 kf = *reinterpret_cast<const bf16x8*>(Kc + kl * 128 + ((kk * 64 + g * 16) ^ sw));
                    sacc[nj] = mfma16(kf, qf[kk], sacc[nj]);
                }
            }
            __builtin_amdgcn_s_setprio(0);

            // in-lane online softmax; scores already scaled (log2 units)
            const bool diag = (it == nt - 1);
            float sv[4][4];
            float tmax = -1e30f;
#pragma unroll
            for (int nj = 0; nj < 4; ++nj)
#pragma unroll
                for (int r = 0; r < 4; ++r) {
                    float s = sacc[nj][r];
                    if (diag && (kb + nj * 16 + g * 4 + r > q)) s = -1e30f;
                    sv[nj][r] = s;
                    tmax = fmaxf(tmax, s);
                }
            tmax = fmaxf(tmax, __shfl_xor(tmax, 16));
            tmax = fmaxf(tmax, __shfl_xor(tmax, 32));

            float alpha = 1.0f;
            if (__any(tmax > mrun + DEFER_THR)) {   // T13: defer-max
                float mnew = fmaxf(mrun, tmax);
                alpha = exp2f(mrun - mnew);
                mrun = mnew;
                float ar[4];
#pragma unroll
                for (int r = 0; r < 4; ++r) ar[r] = __shfl(alpha, g * 4 + r, 16);
#pragma unroll
                for (int f = 0; f < 4; ++f)
#pragma unroll
                    for (int r = 0; r < 4; ++r) oacc[f][r] *= ar[r];
            }

            float rsum = 0.f;
#pragma unroll
            for (int nj = 0; nj < 4; ++nj) {
                float p0 = exp2f(sv[nj][0] - mrun);
                float p1 = exp2f(sv[nj][1] - mrun);
                float p2 = exp2f(sv[nj][2] - mrun);
                float p3 = exp2f(sv[nj][3] - mrun);
                rsum += (p0 + p1) + (p2 + p3);
                uint2 pw = { cvtpk_bf16(p0, p1), cvtpk_bf16(p2, p3) };
                *reinterpret_cast<uint2*>(Pw + c15 * 128 + ((nj * 32 + g * 8) ^ psw)) = pw;
            }
            rsum += __shfl_xor(rsum, 16);
            rsum += __shfl_xor(rsum, 32);
            lrun = lrun * alpha + rsum;

            // O += P V
            bf16x8 pf[2];
#pragma unroll
            for (int kk = 0; kk < 2; ++kk)
                pf[kk] = *reinterpret_cast<const bf16x8*>(Pw + c15 * 128 + ((kk * 64 + g * 16) ^ psw));
            uint32_t vbase = lds_off(Vc) + c15 * 8;
            uint2 vt[4][2][2];
#pragma unroll
            for (int f = 0; f < 4; ++f)
#pragma unroll
                for (int kk = 0; kk < 2; ++kk)
#pragma unroll
                    for (int hh = 0; hh < 2; ++hh)
                        vt[f][kk][hh] = ds_tr16(vbase + (uint32_t)((kk * 8 + g * 2 + hh) * 512 + f * 128));
            asm volatile("s_waitcnt lgkmcnt(0)" ::: "memory");
            __builtin_amdgcn_sched_barrier(0);
            __builtin_amdgcn_s_setprio(1);
#pragma unroll
            for (int f = 0; f < 4; ++f)
#pragma unroll
                for (int kk = 0; kk < 2; ++kk) {
                    union { uint32_t u[4]; bf16x8 v; } fu;
                    fu.u[0] = vt[f][kk][0].x; fu.u[1] = vt[f][kk][0].y;
                    fu.u[2] = vt[f][kk][1].x; fu.u[3] = vt[f][kk][1].y;
                    oacc[f] = mfma16(pf[kk], fu.v, oacc[f]);
                }
            __builtin_amdgcn_s_setprio(0);
            __syncthreads();
        }

        float li = 1.f / lrun;
        float lr[4];
#pragma unroll
        for (int r = 0; r < 4; ++r) lr[r] = __shfl(li, g * 4 + r, 16);
#pragma unroll
        for (int f = 0; f < 4; ++f)
#pragma unroll
            for (int r = 0; r < 4; ++r) {
                int qq = q0 + w * 16 + g * 4 + r;
                O[base_bh + (size_t)qq * D_MODEL + f * 16 + c15] = f2bf(oacc[f][r] * lr[r]);
            }
    }
}

// ---------------- launch ----------------
extern "C" void kernel_launch(void* const* d_in, const int* in_sizes, int n_in,
                              void* d_out, int out_size, void* d_ws, size_t ws_size,
                              hipStream_t stream) {
    const float* x  = (const float*)d_in[0];
    const float* wq = (const float*)d_in[1];
    const float* wk = (const float*)d_in[2];
    const float* wv = (const float*)d_in[3];
    const float* wo = (const float*)d_in[4];
    const float* qg = (const float*)d_in[5];
    const float* kg = (const float*)d_in[6];
    float* out = (float*)d_out;

    char* ws = (char*)d_ws;
    const size_t MB = 1024ull * 1024ull;
    unsigned short* xb  = (unsigned short*)(ws);
    unsigned short* qb  = (unsigned short*)(ws + 8 * MB);
    unsigned short* kb  = (unsigned short*)(ws + 16 * MB);
    unsigned short* vb  = (unsigned short*)(ws + 24 * MB);
    unsigned short* ab  = (unsigned short*)(ws + 32 * MB);
    unsigned short* wqb = (unsigned short*)(ws + 40 * MB);
    unsigned short* wkb = (unsigned short*)(ws + 42 * MB);
    unsigned short* wvb = (unsigned short*)(ws + 44 * MB);
    unsigned short* wob = (unsigned short*)(ws + 46 * MB);
    float2* tab2        = (float2*)(ws + 48 * MB);

    prep_kernel<<<8448, 256, 0, stream>>>(x, wq, wk, wv, wo, xb, wqb, wkb, wvb, wob, tab2);

    gemm_qkv_kernel<<<dim3(24, 32), 256, 0, stream>>>(
        xb, wqb, wkb, wvb, qb, kb, vb, qg, kg, tab2);

    attn_kernel<<<dim3(16, 32), 256, 0, stream>>>(qb, kb, vb, ab);

    gemm_proj_kernel<<<dim3(8, 32), 256, 0, stream>>>(ab, wob, out);
}